// Round 13
// baseline (749.193 us; speedup 1.0000x reference)
//
#include <hip/hip_runtime.h>
#include <hip/hip_cooperative_groups.h>

namespace cg = cooperative_groups;

#define NN      4096
#define FEAT    512
#define KDIM    576          // 512 feature cols + 64 adj_ad relation cols
#define NHID    64
#define NHEADS  8
#define NCLS    16
#define MAXDEG  128
#define ALPHA   0.2f
#define GRID    512          // 2 blocks/CU x 256 CUs — safe cooperative size

typedef __bf16 bf16_t;
typedef __bf16 bf16x8_t __attribute__((ext_vector_type(8)));
typedef float  f32x4_t  __attribute__((ext_vector_type(4)));
typedef unsigned short us8_t __attribute__((ext_vector_type(8)));

__device__ inline unsigned short f2bf(float f) {
    unsigned int u = __float_as_uint(f);
    u += 0x7fffu + ((u >> 16) & 1u);          // round-to-nearest-even
    return (unsigned short)(u >> 16);
}
__device__ inline float bfu2f(unsigned short b) {
    return __uint_as_float(((unsigned int)b) << 16);
}
// async global->LDS, 16B per lane (dst = wave-uniform base + lane*16)
__device__ inline void gload16(const void* g, void* s) {
    __builtin_amdgcn_global_load_lds(
        (const __attribute__((address_space(1))) void*)g,
        (__attribute__((address_space(3))) void*)s, 16, 0, 0);
}

// LDS union: max member = gemm double-buffer 32 KB -> 2 blocks/CU trivially.
union SmU {
    bf16_t g[2][2][64][64];               // gemm dbuf [buf][A|B], 32 KB
    float  p[64 * 65];                    // prep relW srow / transpose tile
    struct {
        int jl[MAXDEG]; float se[NHEADS][MAXDEG];
        float part[4][FEAT]; float sinv[NHEADS]; int sdeg;
    } a1;
    struct {
        int jl[MAXDEG]; float sp[MAXDEG]; float red[4];
        float clsred[16][NCLS]; float sl[NCLS]; int sdeg;
    } a2;
};

// prep virtual-block ranges
#define PREP_REL0   0
#define PREP_TR0    256
#define PREP_Z0     384
#define PREP_CAST0  520
#define PREP_CSR0   2568
#define PREP_NBLK   3592

// ---------------------------------------------------------------------------
// 64x64-tile GEMM body (2-phase dbuf gload_lds pipeline, XOR chunk swizzle).
// layer1: Cbf + f1/f2 dots (head = by). layer2: f-dots + G = C@linW only.
__device__ __forceinline__ void gemm_body(
    SmU& sm, int bid, int t,
    const bf16_t* A, const bf16_t* Bt, unsigned short* Cbf,
    const float* a1, const float* a2, float* f1, float* f2,
    int layer2, const float* linW, float* G) {
    const int bm = (bid >> 3) * 64;
    const int by = bid & 7;
    const int bn = by * 64;
    const int l  = t & 63;
    const int w  = t >> 6;            // wave 0..3
    const int wr = w >> 1;            // wave row half (32 rows)
    const int wc = w & 1;             // wave col half (32 cols)
    const int c16 = l & 15;
    const int q8  = (l >> 4) * 8;     // k-elem offset of this lane's fragment
    const int r4  = (l >> 4) * 4;     // row offset of this lane's acc elems

    const bf16_t* Abase = A  + (size_t)bm * KDIM;
    const bf16_t* Bbase = Bt + (size_t)bn * KDIM;

    auto STAGE = [&](int d, int k0) {
        #pragma unroll
        for (int c = 0; c < 2; ++c) {
            int cb = c * 256 + w * 64;            // wave-uniform chunk base
            int li = cb + l;
            int r = li >> 3, pc = li & 7;
            int lc = pc ^ (r & 7);                // logical chunk to fetch
            gload16(Abase + (size_t)r * KDIM + k0 + lc * 8,
                    (char*)&sm.g[d][0][0][0] + cb * 16);
        }
        #pragma unroll
        for (int c = 0; c < 2; ++c) {
            int cb = c * 256 + w * 64;
            int li = cb + l;
            int r = li >> 3, pc = li & 7;
            int lc = pc ^ (r & 7);
            gload16(Bbase + (size_t)r * KDIM + k0 + lc * 8,
                    (char*)&sm.g[d][1][0][0] + cb * 16);
        }
    };

    f32x4_t acc[2][2] = {};
    int cur = 0;
    STAGE(0, 0);
    __syncthreads();                  // vmcnt(0)+barrier: buf0 ready
    for (int step = 0; step < KDIM / 64; ++step) {
        if (step + 1 < KDIM / 64) STAGE(cur ^ 1, (step + 1) * 64);
        #pragma unroll
        for (int kk = 0; kk < 64; kk += 32) {
            const int ck = (kk + q8) >> 3;        // logical chunk of fragment
            bf16x8_t af[2], bfr[2];
            #pragma unroll
            for (int mi = 0; mi < 2; ++mi) {
                int R = wr * 32 + mi * 16 + c16;
                af[mi] = *(const bf16x8_t*)&sm.g[cur][0][R][(ck ^ (R & 7)) * 8];
            }
            #pragma unroll
            for (int ni = 0; ni < 2; ++ni) {
                int R = wc * 32 + ni * 16 + c16;
                bfr[ni] = *(const bf16x8_t*)&sm.g[cur][1][R][(ck ^ (R & 7)) * 8];
            }
            #pragma unroll
            for (int mi = 0; mi < 2; ++mi)
                #pragma unroll
                for (int ni = 0; ni < 2; ++ni)
                    acc[mi][ni] = __builtin_amdgcn_mfma_f32_16x16x32_bf16(
                        af[mi], bfr[ni], acc[mi][ni], 0, 0, 0);
        }
        __syncthreads();              // drains next-tile loads AFTER compute
        cur ^= 1;
    }
    // C/D layout: col = lane&15, row = (lane>>4)*4 + reg
    float* Ct = (float*)&sm.g[0][0][0][0];        // free after final barrier
    if (layer2) {
        #pragma unroll
        for (int mi = 0; mi < 2; ++mi)
            #pragma unroll
            for (int ni = 0; ni < 2; ++ni)
                #pragma unroll
                for (int r = 0; r < 4; ++r)
                    Ct[(wr * 32 + mi * 16 + r4 + r) * 64
                       + wc * 32 + ni * 16 + c16] = acc[mi][ni][r];
    } else {
        #pragma unroll
        for (int mi = 0; mi < 2; ++mi)
            #pragma unroll
            for (int ni = 0; ni < 2; ++ni)
                #pragma unroll
                for (int r = 0; r < 4; ++r)
                    Cbf[(size_t)(bm + wr * 32 + mi * 16 + r4 + r) * FEAT
                        + bn + wc * 32 + ni * 16 + c16] = f2bf(acc[mi][ni][r]);
    }

    // fused f1/f2 dots (wave covers 32 of 64 cols; cross-wave via atomicAdd)
    float a1v[2], a2v[2];
    #pragma unroll
    for (int ni = 0; ni < 2; ++ni) {
        a1v[ni] = a1[bn + wc * 32 + ni * 16 + c16];
        a2v[ni] = a2[bn + wc * 32 + ni * 16 + c16];
    }
    float p1[2][4] = {}, p2[2][4] = {};
    #pragma unroll
    for (int mi = 0; mi < 2; ++mi)
        #pragma unroll
        for (int ni = 0; ni < 2; ++ni)
            #pragma unroll
            for (int r = 0; r < 4; ++r) {
                p1[mi][r] += acc[mi][ni][r] * a1v[ni];
                p2[mi][r] += acc[mi][ni][r] * a2v[ni];
            }
    #pragma unroll
    for (int off = 1; off <= 8; off <<= 1)
        #pragma unroll
        for (int mi = 0; mi < 2; ++mi)
            #pragma unroll
            for (int r = 0; r < 4; ++r) {
                p1[mi][r] += __shfl_xor(p1[mi][r], off);
                p2[mi][r] += __shfl_xor(p2[mi][r], off);
            }
    if (c16 == 0) {
        int fbase = layer2 ? 0 : by * NN;
        #pragma unroll
        for (int mi = 0; mi < 2; ++mi)
            #pragma unroll
            for (int r = 0; r < 4; ++r) {
                int row = bm + wr * 32 + mi * 16 + r4 + r;
                atomicAdd(&f1[fbase + row], p1[mi][r]);
                atomicAdd(&f2[fbase + row], p2[mi][r]);
            }
    }
    // ---- G partial: G[bm+row][cls] += sum_c Ct[row][c]*linW[bn+c][cls] ----
    if (layer2) {
        __syncthreads();              // Ct fully written
        int row = t >> 2;             // 0..63
        int cls0 = (t & 3) * 4;       // 4 consecutive classes
        float pg[4] = {};
        #pragma unroll 8
        for (int c = 0; c < 64; ++c) {
            float cv = Ct[row * 64 + c];
            float4 wv = *(const float4*)&linW[(size_t)(bn + c) * NCLS + cls0];
            pg[0] += cv * wv.x; pg[1] += cv * wv.y;
            pg[2] += cv * wv.z; pg[3] += cv * wv.w;
        }
        #pragma unroll
        for (int j = 0; j < 4; ++j)
            atomicAdd(&G[(size_t)(bm + row) * NCLS + cls0 + j], pg[j]);
    }
    __syncthreads();                  // sm reuse safety before next phase
}

// ---------------------------------------------------------------------------
// Cooperative mega-kernel: prep | gemm1 | att1 | gemm2 | att2 in one launch.
__global__ __launch_bounds__(256, 2) void gat_mega(
    const float* x, const float* rel, const float* adj, const float* adj_ad,
    const float* Wh, const float* a1h, const float* a2h,
    const float* Wo, const float* a1o, const float* a2o,
    const float* linW, const float* linb, float* out,
    bf16_t* Abf, bf16_t* Abf2, bf16_t* Hbf1,
    unsigned short* WcT, unsigned short* WoT,
    float* f1, float* f2, float* f1o, float* f2o, float* G,
    int* deg, int* cols) {
    cg::grid_group grid = cg::this_grid();
    const int b = blockIdx.x;
    const int t = threadIdx.x;
    __shared__ __align__(16) SmU sm;

    // ==== P1: front-end (relW, transposes, zero, A_ext casts, CSR) ====
    for (int vb = b; vb < PREP_NBLK; vb += GRID) {
        if (vb < PREP_TR0) {
            int r  = vb & 63;
            int nh = (vb >> 6) & 1;
            int n  = nh * 256 + t;
            sm.p[t]       = rel[r * FEAT + t];
            sm.p[t + 256] = rel[r * FEAT + 256 + t];
            __syncthreads();
            float acc[8] = {};
            if (vb < 128) {           // relWc[r][n] = sum_k rel[r,k] Wh[h,k,f]
                int h = n >> 6, f = n & 63;
                const float* p = Wh + (size_t)h * 32768 + f;
                for (int k0 = 0; k0 < 512; k0 += 8)
                    #pragma unroll
                    for (int u = 0; u < 8; ++u)
                        acc[u] += sm.p[k0 + u] * p[(size_t)(k0 + u) * 64];
                float s = ((acc[0] + acc[1]) + (acc[2] + acc[3]))
                        + ((acc[4] + acc[5]) + (acc[6] + acc[7]));
                WcT[(size_t)n * KDIM + 512 + r] = f2bf(s);
            } else {                  // relWo[r][n] = sum_k rel[r,k] Wo[k,n]
                const float* p = Wo + n;
                for (int k0 = 0; k0 < 512; k0 += 8)
                    #pragma unroll
                    for (int u = 0; u < 8; ++u)
                        acc[u] += sm.p[k0 + u] * p[(size_t)(k0 + u) * 512];
                float s = ((acc[0] + acc[1]) + (acc[2] + acc[3]))
                        + ((acc[4] + acc[5]) + (acc[6] + acc[7]));
                WoT[(size_t)n * KDIM + 512 + r] = f2bf(s);
            }
        } else if (vb < PREP_Z0) {
            int tb = vb - PREP_TR0;   // 0..127: [0,64) Wc, [64,128) Wo
            if (tb < 64) {
                int h = tb >> 3, k0 = (tb & 7) * 64;
                const float* src = Wh + (size_t)h * 32768 + (size_t)k0 * 64;
                #pragma unroll
                for (int i2 = 0; i2 < 16; ++i2) {
                    int li = t + i2 * 256;
                    float v = src[li];
                    sm.p[(li & 63) * 65 + (li >> 6)] = v;
                }
                __syncthreads();
                #pragma unroll
                for (int i2 = 0; i2 < 16; ++i2) {
                    int li = t + i2 * 256;
                    int f = li >> 6, r = li & 63;
                    WcT[(size_t)(h * 64 + f) * KDIM + k0 + r] = f2bf(sm.p[f * 65 + r]);
                }
            } else {
                int wb = tb - 64;
                int n0 = (wb & 7) * 64, k0 = (wb >> 3) * 64;
                #pragma unroll
                for (int i2 = 0; i2 < 16; ++i2) {
                    int li = t + i2 * 256;
                    int r = li >> 6, f = li & 63;
                    float v = Wo[(size_t)(k0 + r) * 512 + n0 + f];
                    sm.p[f * 65 + r] = v;
                }
                __syncthreads();
                #pragma unroll
                for (int i2 = 0; i2 < 16; ++i2) {
                    int li = t + i2 * 256;
                    int f = li >> 6, r = li & 63;
                    WoT[(size_t)(n0 + f) * KDIM + k0 + r] = f2bf(sm.p[f * 65 + r]);
                }
            }
        } else if (vb < PREP_CAST0) {
            int g = (vb - PREP_Z0) * 256 + t;
            ((float4*)f1)[g] = make_float4(0.f, 0.f, 0.f, 0.f);
        } else if (vb < PREP_CSR0) {
            int half = t >> 7;
            int tt = t & 127;
            size_t i = (size_t)(vb - PREP_CAST0) * 2 + half;
            float4 xv = ((const float4*)(x + i * FEAT))[tt];
            ushort4 o;
            o.x = f2bf(xv.x); o.y = f2bf(xv.y);
            o.z = f2bf(xv.z); o.w = f2bf(xv.w);
            *(ushort4*)(Abf + i * KDIM + 4 * tt) = o;
            if (tt < 16) {
                float4 av = ((const float4*)(adj_ad + i * 64))[tt];
                ushort4 o2;
                o2.x = f2bf(av.x); o2.y = f2bf(av.y);
                o2.z = f2bf(av.z); o2.w = f2bf(av.w);
                *(ushort4*)(Abf  + i * KDIM + 512 + 4 * tt) = o2;
                *(ushort4*)(Abf2 + i * KDIM + 512 + 4 * tt) = o2;
            }
        } else {
            int l = t & 63;
            int i = (vb - PREP_CSR0) * 4 + (t >> 6);
            const float4* row4 = (const float4*)(adj + (size_t)i * NN);
            float4 v[16];
            #pragma unroll
            for (int c2 = 0; c2 < 16; ++c2) v[c2] = row4[l + c2 * 64];
            unsigned long long mask = 0;
            #pragma unroll
            for (int c2 = 0; c2 < 16; ++c2) {
                unsigned m4 = (unsigned)(v[c2].x > 0.0f)
                            | ((unsigned)(v[c2].y > 0.0f) << 1)
                            | ((unsigned)(v[c2].z > 0.0f) << 2)
                            | ((unsigned)(v[c2].w > 0.0f) << 3);
                mask |= (unsigned long long)m4 << (4 * c2);
            }
            int c = __popcll(mask);
            int pre = c;
            #pragma unroll
            for (int off = 1; off < 64; off <<= 1) {
                int n = __shfl_up(pre, off);
                if (l >= off) pre += n;
            }
            int base = pre - c;
            if (l == 63) deg[i] = pre > MAXDEG ? MAXDEG : pre;
            int* colrow = cols + i * MAXDEG;
            int idx = base;
            while (mask) {
                int bit = (int)__ffsll(mask) - 1;
                mask &= mask - 1;
                int j = 4 * l + ((bit >> 2) << 8) + (bit & 3);
                if (idx < MAXDEG) colrow[idx] = j;
                ++idx;
            }
        }
        __syncthreads();              // sm reuse across virtual blocks
    }
    __threadfence_system();
    grid.sync();
    __threadfence_system();

    // ==== P2: layer-1 GEMM (512 tile-blocks) ====
    if (b < 512)
        gemm_body(sm, b, t, Abf, (const bf16_t*)WcT, (unsigned short*)Hbf1,
                  a1h, a2h, f1, f2, 0, nullptr, nullptr);
    __threadfence_system();
    grid.sync();
    __threadfence_system();

    // ==== P3: layer-1 attention (4 waves; 2 heads/wave phase A) ====
    {
        const int w = t >> 6, l = t & 63;
        const int myhead = l >> 3;
        for (int i = b; i < NN; i += GRID) {
            if (t == 0) sm.a1.sdeg = deg[i];
            __syncthreads();
            int d = sm.a1.sdeg;
            int dpad = (d + 31) & ~31;        // 4 slots x 8 unroll
            for (int k = t; k < dpad; k += 256)
                sm.a1.jl[k] = (k < d) ? cols[i * MAXDEG + k] : i;
            __syncthreads();
            for (int hh = w; hh < NHEADS; hh += 4) {
                float fi = f1[hh * NN + i];
                float lmax = -1e30f;
                for (int k = l; k < d; k += 64) {
                    float e = fi + f2[hh * NN + sm.a1.jl[k]];
                    e = e > 0.0f ? e : ALPHA * e;
                    sm.a1.se[hh][k] = e;
                    lmax = fmaxf(lmax, e);
                }
                for (int off = 32; off; off >>= 1)
                    lmax = fmaxf(lmax, __shfl_down(lmax, off));
                float m = __shfl(lmax, 0);
                float ls = 0.0f;
                for (int k = l; k < d; k += 64) {
                    float p = __expf(sm.a1.se[hh][k] - m);
                    sm.a1.se[hh][k] = p;
                    ls += p;
                }
                for (int k = d + l; k < dpad; k += 64) sm.a1.se[hh][k] = 0.0f;
                for (int off = 32; off; off >>= 1) ls += __shfl_down(ls, off);
                if (l == 0) sm.a1.sinv[hh] = 1.0f / ls;
            }
            __syncthreads();
            float acc[8] = {};
            for (int k0 = 0; k0 < dpad; k0 += 32) {
                float pw[8];
                const bf16_t* rp[8];
                #pragma unroll
                for (int j = 0; j < 8; ++j) {
                    int k = k0 + j * 4 + w;          // k < dpad guaranteed
                    pw[j] = sm.a1.se[myhead][k];
                    rp[j] = Hbf1 + (size_t)sm.a1.jl[k] * FEAT + l * 8;
                }
                #pragma unroll
                for (int j = 0; j < 8; ++j) {
                    us8_t v = *(const us8_t*)rp[j];
                    float p = pw[j];
                    #pragma unroll
                    for (int q = 0; q < 8; ++q) acc[q] += p * bfu2f(v[q]);
                }
            }
            *(float4*)&sm.a1.part[w][l * 8]     = make_float4(acc[0], acc[1], acc[2], acc[3]);
            *(float4*)&sm.a1.part[w][l * 8 + 4] = make_float4(acc[4], acc[5], acc[6], acc[7]);
            __syncthreads();
            #pragma unroll
            for (int cc = 0; cc < 2; ++cc) {
                int c = t + cc * 256;
                float sum = sm.a1.part[0][c] + sm.a1.part[1][c]
                          + sm.a1.part[2][c] + sm.a1.part[3][c];
                float o = sum * sm.a1.sinv[c >> 6];
                o = o > 0.0f ? o : __expf(o) - 1.0f; // ELU
                ((unsigned short*)Abf2)[(size_t)i * KDIM + c] = f2bf(o);
            }
            __syncthreads();          // sm reuse before next row
        }
    }
    __threadfence_system();
    grid.sync();
    __threadfence_system();

    // ==== P4: layer-2 GEMM (512 tile-blocks) + G = C@linW ====
    if (b < 512)
        gemm_body(sm, b, t, Abf2, (const bf16_t*)WoT, nullptr,
                  a1o, a2o, f1o, f2o, 1, linW, G);
    __threadfence_system();
    grid.sync();
    __threadfence_system();

    // ==== P5: layer-2 attention on G + classifier + log_softmax ====
    for (int i = b; i < NN; i += GRID) {
        if (t == 0) sm.a2.sdeg = deg[i];
        __syncthreads();
        int d = sm.a2.sdeg;
        int dpad = (d + 15) & ~15;
        if (t < dpad) sm.a2.jl[t] = (t < d) ? cols[i * MAXDEG + t] : i;
        __syncthreads();
        float e = 0.0f, lmax = -1e30f;
        if (t < d) {
            e = f1o[i] + f2o[sm.a2.jl[t]];
            e = e > 0.0f ? e : ALPHA * e;
            lmax = e;
        }
        for (int off = 32; off; off >>= 1) lmax = fmaxf(lmax, __shfl_down(lmax, off));
        if ((t & 63) == 0) sm.a2.red[t >> 6] = lmax;
        __syncthreads();
        float m = fmaxf(fmaxf(sm.a2.red[0], sm.a2.red[1]),
                        fmaxf(sm.a2.red[2], sm.a2.red[3]));
        float p = 0.0f;
        if (t < d) p = __expf(e - m);
        if (t < dpad) sm.a2.sp[t] = p;
        float ls = p;
        for (int off = 32; off; off >>= 1) ls += __shfl_down(ls, off);
        __syncthreads();
        if ((t & 63) == 0) sm.a2.red[t >> 6] = ls;
        __syncthreads();
        float s = sm.a2.red[0] + sm.a2.red[1] + sm.a2.red[2] + sm.a2.red[3];
        float inv = 1.0f / s;
        {
            int slot = t >> 4;
            int cls  = t & 15;
            float fa[4] = {};
            for (int k = slot; k < dpad; k += 16)
                fa[(k >> 4) & 3] += sm.a2.sp[k] * G[(size_t)sm.a2.jl[k] * NCLS + cls];
            sm.a2.clsred[slot][cls] = (fa[0] + fa[1]) + (fa[2] + fa[3]);
        }
        __syncthreads();
        if (t < NCLS) {
            float dot = 0.0f;
            #pragma unroll
            for (int seg = 0; seg < 16; ++seg) dot += sm.a2.clsred[seg][t];
            float logit = linb[t] + dot * inv;
            logit = logit > 0.0f ? logit : __expf(logit) - 1.0f;   // ELU
            sm.a2.sl[t] = logit;
        }
        __syncthreads();
        if (t < NCLS) {
            float mm = sm.a2.sl[0];
            #pragma unroll
            for (int c = 1; c < NCLS; ++c) mm = fmaxf(mm, sm.a2.sl[c]);
            float ssum = 0.0f;
            #pragma unroll
            for (int c = 0; c < NCLS; ++c) ssum += __expf(sm.a2.sl[c] - mm);
            out[i * NCLS + t] = sm.a2.sl[t] - mm - logf(ssum);
        }
        __syncthreads();              // sm reuse before next row
    }
}

// ---------------------------------------------------------------------------
// Fallback kernels (round-11 pipeline, proven at 186.9 us) — used if the
// cooperative launch is rejected by the runtime.
__global__ __launch_bounds__(256) void prep_kernel(
    const float* __restrict__ adj, int* __restrict__ deg, int* __restrict__ cols,
    const float* __restrict__ adj_ad, const float* __restrict__ rel,
    const float* __restrict__ x, bf16_t* __restrict__ Abf,
    bf16_t* __restrict__ Abf2,
    const float* __restrict__ Wh, const float* __restrict__ Wo,
    unsigned short* __restrict__ WcT, unsigned short* __restrict__ WoT,
    float* __restrict__ fzero) {
    int b = blockIdx.x;
    int t = threadIdx.x;
    __shared__ float smem[64 * 65];
    if (b < PREP_TR0) {
        int r  = b & 63;
        int nh = (b >> 6) & 1;
        int n  = nh * 256 + t;
        smem[t]       = rel[r * FEAT + t];
        smem[t + 256] = rel[r * FEAT + 256 + t];
        __syncthreads();
        float acc[8] = {};
        if (b < 128) {
            int h = n >> 6, f = n & 63;
            const float* p = Wh + (size_t)h * 32768 + f;
            for (int k0 = 0; k0 < 512; k0 += 8)
                #pragma unroll
                for (int u = 0; u < 8; ++u)
                    acc[u] += smem[k0 + u] * p[(size_t)(k0 + u) * 64];
            float s = ((acc[0] + acc[1]) + (acc[2] + acc[3]))
                    + ((acc[4] + acc[5]) + (acc[6] + acc[7]));
            WcT[(size_t)n * KDIM + 512 + r] = f2bf(s);
        } else {
            const float* p = Wo + n;
            for (int k0 = 0; k0 < 512; k0 += 8)
                #pragma unroll
                for (int u = 0; u < 8; ++u)
                    acc[u] += smem[k0 + u] * p[(size_t)(k0 + u) * 512];
            float s = ((acc[0] + acc[1]) + (acc[2] + acc[3]))
                    + ((acc[4] + acc[5]) + (acc[6] + acc[7]));
            WoT[(size_t)n * KDIM + 512 + r] = f2bf(s);
        }
    } else if (b < PREP_Z0) {
        int tb = b - PREP_TR0;
        if (tb < 64) {
            int h = tb >> 3, k0 = (tb & 7) * 64;
            const float* src = Wh + (size_t)h * 32768 + (size_t)k0 * 64;
            #pragma unroll
            for (int i2 = 0; i2 < 16; ++i2) {
                int li = t + i2 * 256;
                float v = src[li];
                smem[(li & 63) * 65 + (li >> 6)] = v;
            }
            __syncthreads();
            #pragma unroll
            for (int i2 = 0; i2 < 16; ++i2) {
                int li = t + i2 * 256;
                int f = li >> 6, r = li & 63;
                WcT[(size_t)(h * 64 + f) * KDIM + k0 + r] = f2bf(smem[f * 65 + r]);
            }
        } else {
            int wb = tb - 64;
            int n0 = (wb & 7) * 64, k0 = (wb >> 3) * 64;
            #pragma unroll
            for (int i2 = 0; i2 < 16; ++i2) {
                int li = t + i2 * 256;
                int r = li >> 6, f = li & 63;
                float v = Wo[(size_t)(k0 + r) * 512 + n0 + f];
                smem[f * 65 + r] = v;
            }
            __syncthreads();
            #pragma unroll
            for (int i2 = 0; i2 < 16; ++i2) {
                int li = t + i2 * 256;
                int f = li >> 6, r = li & 63;
                WoT[(size_t)(n0 + f) * KDIM + k0 + r] = f2bf(smem[f * 65 + r]);
            }
        }
    } else if (b < PREP_CAST0) {
        int g = (b - PREP_Z0) * 256 + t;
        ((float4*)fzero)[g] = make_float4(0.f, 0.f, 0.f, 0.f);
    } else if (b < PREP_CSR0) {
        int half = t >> 7;
        int tt = t & 127;
        size_t i = (size_t)(b - PREP_CAST0) * 2 + half;
        float4 xv = ((const float4*)(x + i * FEAT))[tt];
        ushort4 o;
        o.x = f2bf(xv.x); o.y = f2bf(xv.y);
        o.z = f2bf(xv.z); o.w = f2bf(xv.w);
        *(ushort4*)(Abf + i * KDIM + 4 * tt) = o;
        if (tt < 16) {
            float4 av = ((const float4*)(adj_ad + i * 64))[tt];
            ushort4 o2;
            o2.x = f2bf(av.x); o2.y = f2bf(av.y);
            o2.z = f2bf(av.z); o2.w = f2bf(av.w);
            *(ushort4*)(Abf  + i * KDIM + 512 + 4 * tt) = o2;
            *(ushort4*)(Abf2 + i * KDIM + 512 + 4 * tt) = o2;
        }
    } else {
        int l = t & 63;
        int i = (b - PREP_CSR0) * 4 + (t >> 6);
        const float4* row4 = (const float4*)(adj + (size_t)i * NN);
        float4 v[16];
        #pragma unroll
        for (int c2 = 0; c2 < 16; ++c2) v[c2] = row4[l + c2 * 64];
        unsigned long long mask = 0;
        #pragma unroll
        for (int c2 = 0; c2 < 16; ++c2) {
            unsigned m4 = (unsigned)(v[c2].x > 0.0f)
                        | ((unsigned)(v[c2].y > 0.0f) << 1)
                        | ((unsigned)(v[c2].z > 0.0f) << 2)
                        | ((unsigned)(v[c2].w > 0.0f) << 3);
            mask |= (unsigned long long)m4 << (4 * c2);
        }
        int c = __popcll(mask);
        int pre = c;
        #pragma unroll
        for (int off = 1; off < 64; off <<= 1) {
            int n = __shfl_up(pre, off);
            if (l >= off) pre += n;
        }
        int base = pre - c;
        if (l == 63) deg[i] = pre > MAXDEG ? MAXDEG : pre;
        int* colrow = cols + i * MAXDEG;
        int idx = base;
        while (mask) {
            int bit = (int)__ffsll(mask) - 1;
            mask &= mask - 1;
            int j = 4 * l + ((bit >> 2) << 8) + (bit & 3);
            if (idx < MAXDEG) colrow[idx] = j;
            ++idx;
        }
    }
}

__global__ __launch_bounds__(256) void gemm_fb_kernel(
    const bf16_t* __restrict__ A, const bf16_t* __restrict__ Bt,
    unsigned short* __restrict__ Cbf,
    const float* __restrict__ a1, const float* __restrict__ a2,
    float* __restrict__ f1, float* __restrict__ f2, int layer2,
    const float* __restrict__ linW, float* __restrict__ G) {
    __shared__ __align__(16) SmU sm;
    gemm_body(sm, blockIdx.x, threadIdx.x, A, Bt, Cbf, a1, a2, f1, f2,
              layer2, linW, G);
}

__global__ __launch_bounds__(512) void att1_kernel(
    const bf16_t* __restrict__ Hbf, const float* __restrict__ f1,
    const float* __restrict__ f2, const int* __restrict__ deg,
    const int* __restrict__ cols, bf16_t* __restrict__ outbf) {
    int i = blockIdx.x;
    int tid = threadIdx.x;
    int h = tid >> 6;
    int l = tid & 63;
    __shared__ int jl[MAXDEG];
    __shared__ float se[NHEADS][MAXDEG];
    __shared__ float part[NHEADS][FEAT];
    __shared__ float sinv[NHEADS];
    __shared__ int sdeg;
    if (tid == 0) sdeg = deg[i];
    __syncthreads();
    int d = sdeg;
    int dpad = (d + 31) & ~31;
    for (int k = tid; k < dpad; k += 512)
        jl[k] = (k < d) ? cols[i * MAXDEG + k] : i;
    __syncthreads();
    float fi = f1[h * NN + i];
    float lmax = -1e30f;
    for (int k = l; k < d; k += 64) {
        float e = fi + f2[h * NN + jl[k]];
        e = e > 0.0f ? e : ALPHA * e;
        se[h][k] = e;
        lmax = fmaxf(lmax, e);
    }
    for (int off = 32; off; off >>= 1) lmax = fmaxf(lmax, __shfl_down(lmax, off));
    float m = __shfl(lmax, 0);
    float ls = 0.0f;
    for (int k = l; k < d; k += 64) {
        float p = __expf(se[h][k] - m);
        se[h][k] = p;
        ls += p;
    }
    for (int k = d + l; k < dpad; k += 64) se[h][k] = 0.0f;
    for (int off = 32; off; off >>= 1) ls += __shfl_down(ls, off);
    if (l == 0) sinv[h] = 1.0f / ls;
    __syncthreads();
    const int myhead = l >> 3;
    float acc[8] = {};
    for (int k0 = 0; k0 < dpad; k0 += 32) {
        float pw[4];
        const bf16_t* rp[4];
        #pragma unroll
        for (int j = 0; j < 4; ++j) {
            int k = k0 + j * 8 + h;
            pw[j] = se[myhead][k];
            rp[j] = Hbf + (size_t)jl[k] * FEAT + l * 8;
        }
        #pragma unroll
        for (int j = 0; j < 4; ++j) {
            us8_t v = *(const us8_t*)rp[j];
            float p = pw[j];
            #pragma unroll
            for (int q = 0; q < 8; ++q) acc[q] += p * bfu2f(v[q]);
        }
    }
    *(float4*)&part[h][l * 8]     = make_float4(acc[0], acc[1], acc[2], acc[3]);
    *(float4*)&part[h][l * 8 + 4] = make_float4(acc[4], acc[5], acc[6], acc[7]);
    __syncthreads();
    {
        float sum = 0.0f;
        #pragma unroll
        for (int w2 = 0; w2 < NHEADS; ++w2) sum += part[w2][tid];
        float o = sum * sinv[tid >> 6];
        o = o > 0.0f ? o : __expf(o) - 1.0f;
        ((unsigned short*)outbf)[(size_t)i * KDIM + tid] = f2bf(o);
    }
}

__global__ __launch_bounds__(256) void att2_final_kernel(
    const float* __restrict__ G, const float* __restrict__ f1,
    const float* __restrict__ f2, const int* __restrict__ deg,
    const int* __restrict__ cols, const float* __restrict__ linb,
    float* __restrict__ out) {
    int i = blockIdx.x;
    int t = threadIdx.x;
    __shared__ int jl[MAXDEG];
    __shared__ float sp[MAXDEG];
    __shared__ float red[4];
    __shared__ float clsred[16][NCLS];
    __shared__ float sl[NCLS];
    __shared__ int sdeg;
    if (t == 0) sdeg = deg[i];
    __syncthreads();
    int d = sdeg;
    int dpad = (d + 15) & ~15;
    if (t < dpad) jl[t] = (t < d) ? cols[i * MAXDEG + t] : i;
    __syncthreads();
    float e = 0.0f, lmax = -1e30f;
    if (t < d) {
        e = f1[i] + f2[jl[t]];
        e = e > 0.0f ? e : ALPHA * e;
        lmax = e;
    }
    for (int off = 32; off; off >>= 1) lmax = fmaxf(lmax, __shfl_down(lmax, off));
    if ((t & 63) == 0) red[t >> 6] = lmax;
    __syncthreads();
    float m = fmaxf(fmaxf(red[0], red[1]), fmaxf(red[2], red[3]));
    float p = 0.0f;
    if (t < d) p = __expf(e - m);
    if (t < dpad) sp[t] = p;
    float ls = p;
    for (int off = 32; off; off >>= 1) ls += __shfl_down(ls, off);
    __syncthreads();
    if ((t & 63) == 0) red[t >> 6] = ls;
    __syncthreads();
    float s = red[0] + red[1] + red[2] + red[3];
    float inv = 1.0f / s;
    {
        int slot = t >> 4;
        int cls  = t & 15;
        float fa[4] = {};
        for (int k = slot; k < dpad; k += 16)
            fa[(k >> 4) & 3] += sp[k] * G[(size_t)jl[k] * NCLS + cls];
        clsred[slot][cls] = (fa[0] + fa[1]) + (fa[2] + fa[3]);
    }
    __syncthreads();
    if (t < NCLS) {
        float dot = 0.0f;
        #pragma unroll
        for (int seg = 0; seg < 16; ++seg) dot += clsred[seg][t];
        float logit = linb[t] + dot * inv;
        logit = logit > 0.0f ? logit : __expf(logit) - 1.0f;
        sl[t] = logit;
    }
    __syncthreads();
    if (t < NCLS) {
        float mm = sl[0];
        #pragma unroll
        for (int c = 1; c < NCLS; ++c) mm = fmaxf(mm, sl[c]);
        float ssum = 0.0f;
        #pragma unroll
        for (int c = 0; c < NCLS; ++c) ssum += __expf(sl[c] - mm);
        out[i * NCLS + t] = sl[t] - mm - logf(ssum);
    }
}

// ---------------------------------------------------------------------------
extern "C" void kernel_launch(void* const* d_in, const int* in_sizes, int n_in,
                              void* d_out, int out_size, void* d_ws, size_t ws_size,
                              hipStream_t stream) {
    const float* x        = (const float*)d_in[0];
    const float* rel      = (const float*)d_in[1];
    // d_in[2] rel_dict: unused (non-math constant per reference)
    const float* adj      = (const float*)d_in[3];
    const float* adj_ad   = (const float*)d_in[4];
    const float* W_heads  = (const float*)d_in[5];
    const float* a1_heads = (const float*)d_in[6];
    const float* a2_heads = (const float*)d_in[7];
    const float* W_out    = (const float*)d_in[8];
    const float* a1_out   = (const float*)d_in[9];
    const float* a2_out   = (const float*)d_in[10];
    const float* lin_W    = (const float*)d_in[11];
    const float* lin_b    = (const float*)d_in[12];
    float* out = (float*)d_out;

    char* ws = (char*)d_ws;
    bf16_t* Abf  = (bf16_t*)(ws);                                 // 4.5 MB [4096][576]
    bf16_t* Abf2 = (bf16_t*)(ws + (5u  << 20));                   // 4.5 MB [4096][576]
    bf16_t* Hbf1 = (bf16_t*)(ws + (10u << 20));                   // 4 MB  [4096][512]
    unsigned short* WcTp = (unsigned short*)(ws + (18u << 20));   // 576 KB
    unsigned short* WoTp = (unsigned short*)(ws + (19u << 20));   // 576 KB
    float*  f1   = (float*) (ws + (20u << 20));                   // 128 KB [8,4096]
    float*  f2   = (float*) (ws + (20u << 20) + (128u << 10));    // 128 KB
    float*  f1o  = (float*) (ws + (20u << 20) + (256u << 10));    // 16 KB
    float*  f2o  = (float*) (ws + (20u << 20) + (272u << 10));    // 16 KB
    float*  G    = (float*) (ws + (20u << 20) + (288u << 10));    // 256 KB [4096][16]
    int*    deg  = (int*)   (ws + (20u << 20) + (544u << 10));    // 16 KB
    int*    cols = (int*)   (ws + (21u << 20));                   // 2 MB  [4096,128]

    bf16_t* Abfp = Abf; bf16_t* Abf2p = Abf2; bf16_t* Hbf1p = Hbf1;
    void* args[] = {
        &x, &rel, &adj, &adj_ad, &W_heads, &a1_heads, &a2_heads,
        &W_out, &a1_out, &a2_out, &lin_W, &lin_b, &out,
        &Abfp, &Abf2p, &Hbf1p, &WcTp, &WoTp,
        &f1, &f2, &f1o, &f2o, &G, &deg, &cols };
    hipError_t e = hipLaunchCooperativeKernel(gat_mega, dim3(GRID), dim3(256),
                                              args, 0, stream);
    if (e != hipSuccess) {
        (void)hipGetLastError();      // clear sticky error; run fallback
        prep_kernel<<<PREP_NBLK, 256, 0, stream>>>(
            adj, deg, cols, adj_ad, rel, x, Abf, Abf2, W_heads, W_out,
            WcTp, WoTp, f1);
        gemm_fb_kernel<<<512, 256, 0, stream>>>(
            Abf, (const bf16_t*)WcTp, (unsigned short*)Hbf1,
            a1_heads, a2_heads, f1, f2, 0, nullptr, nullptr);
        att1_kernel<<<NN, 512, 0, stream>>>(Hbf1, f1, f2, deg, cols, Abf2);
        gemm_fb_kernel<<<512, 256, 0, stream>>>(
            Abf2, (const bf16_t*)WoTp, nullptr,
            a1_out, a2_out, f1o, f2o, 1, lin_W, G);
        att2_final_kernel<<<NN, 256, 0, stream>>>(G, f1o, f2o, deg, cols, lin_b, out);
    }
}

// Round 14
// 183.653 us; speedup vs baseline: 4.0794x; 4.0794x over previous
//
#include <hip/hip_runtime.h>

#define NN      4096
#define FEAT    512
#define KDIM    576          // 512 feature cols + 64 adj_ad relation cols
#define NHID    64
#define NHEADS  8
#define NCLS    16
#define MAXDEG  128
#define ALPHA   0.2f

typedef __bf16 bf16_t;
typedef __bf16 bf16x8_t __attribute__((ext_vector_type(8)));
typedef float  f32x4_t  __attribute__((ext_vector_type(4)));
typedef unsigned short us8_t __attribute__((ext_vector_type(8)));

__device__ inline unsigned short f2bf(float f) {
    unsigned int u = __float_as_uint(f);
    u += 0x7fffu + ((u >> 16) & 1u);          // round-to-nearest-even
    return (unsigned short)(u >> 16);
}
__device__ inline float bfu2f(unsigned short b) {
    return __uint_as_float(((unsigned int)b) << 16);
}
// async global->LDS, 16B per lane (dst = wave-uniform base + lane*16)
__device__ inline void gload16(const void* g, void* s) {
    __builtin_amdgcn_global_load_lds(
        (const __attribute__((address_space(1))) void*)g,
        (__attribute__((address_space(3))) void*)s, 16, 0, 0);
}

// ---------------------------------------------------------------------------
// Fused front-end (round-6 form).
//   [0,256):      relW  (rel@Wc, rel@Wo -> B_ext rows 512..575), 8-way ILP
//   [256,384):    weight transposes via LDS 64x64 tiles (coalesced both sides)
//   [384,520):    zero f1/f2/f1o/f2o/G (contiguous 544 KB; GEMMs atomicAdd)
//   [520,2568):   A_ext cast rows (x, adj_ad -> bf16, pitch 576)
//   [2568,3592):  CSR: ONE WAVE PER ROW, no barriers/LDS, 16 loads in flight
#define PREP_REL0   0
#define PREP_TR0    256
#define PREP_Z0     384
#define PREP_CAST0  520
#define PREP_CSR0   2568
#define PREP_NBLK   3592

__global__ __launch_bounds__(256) void prep_kernel(
    const float* __restrict__ adj, int* __restrict__ deg, int* __restrict__ cols,
    const float* __restrict__ adj_ad, const float* __restrict__ rel,
    const float* __restrict__ x, bf16_t* __restrict__ Abf,
    bf16_t* __restrict__ Abf2,
    const float* __restrict__ Wh, const float* __restrict__ Wo,
    unsigned short* __restrict__ WcT, unsigned short* __restrict__ WoT,
    float* __restrict__ fzero) {
    int b = blockIdx.x;
    int t = threadIdx.x;
    __shared__ float smem[64 * 65];       // relW: srow[512]; transpose: tile
    if (b < PREP_TR0) {
        // ---- relW: block = (matrix(1b), n-half(1b), r(6b)); 256 n's/block --
        int r  = b & 63;
        int nh = (b >> 6) & 1;
        int n  = nh * 256 + t;
        smem[t]       = rel[r * FEAT + t];
        smem[t + 256] = rel[r * FEAT + 256 + t];
        __syncthreads();
        float acc[8] = {};
        if (b < 128) {                // relWc[r][n] = sum_k rel[r,k] Wh[h,k,f]
            int h = n >> 6, f = n & 63;
            const float* p = Wh + (size_t)h * 32768 + f;
            for (int k0 = 0; k0 < 512; k0 += 8)
                #pragma unroll
                for (int u = 0; u < 8; ++u)
                    acc[u] += smem[k0 + u] * p[(size_t)(k0 + u) * 64];
            float s = ((acc[0] + acc[1]) + (acc[2] + acc[3]))
                    + ((acc[4] + acc[5]) + (acc[6] + acc[7]));
            WcT[(size_t)n * KDIM + 512 + r] = f2bf(s);
        } else {                      // relWo[r][n] = sum_k rel[r,k] Wo[k,n]
            const float* p = Wo + n;
            for (int k0 = 0; k0 < 512; k0 += 8)
                #pragma unroll
                for (int u = 0; u < 8; ++u)
                    acc[u] += smem[k0 + u] * p[(size_t)(k0 + u) * 512];
            float s = ((acc[0] + acc[1]) + (acc[2] + acc[3]))
                    + ((acc[4] + acc[5]) + (acc[6] + acc[7]));
            WoT[(size_t)n * KDIM + 512 + r] = f2bf(s);
        }
    } else if (b < PREP_Z0) {
        // ---- weight transposes: 64x64 LDS tile, coalesced load AND store --
        int tb = b - PREP_TR0;        // 0..127: [0,64) Wc, [64,128) Wo
        if (tb < 64) {
            // WcT[(h*64+f)*KDIM + k] = Wh[h*32768 + k*64 + f]
            int h = tb >> 3, k0 = (tb & 7) * 64;
            const float* src = Wh + (size_t)h * 32768 + (size_t)k0 * 64;
            #pragma unroll
            for (int i2 = 0; i2 < 16; ++i2) {
                int li = t + i2 * 256;            // r = li>>6, f = li&63
                float v = src[li];                // contiguous
                smem[(li & 63) * 65 + (li >> 6)] = v;   // tile[f][r]
            }
            __syncthreads();
            #pragma unroll
            for (int i2 = 0; i2 < 16; ++i2) {
                int li = t + i2 * 256;
                int f = li >> 6, r = li & 63;
                WcT[(size_t)(h * 64 + f) * KDIM + k0 + r] = f2bf(smem[f * 65 + r]);
            }
        } else {
            // WoT[(n)*KDIM + k] = Wo[k*512 + n]
            int wb = tb - 64;
            int n0 = (wb & 7) * 64, k0 = (wb >> 3) * 64;
            #pragma unroll
            for (int i2 = 0; i2 < 16; ++i2) {
                int li = t + i2 * 256;            // r = li>>6 (k), f = li&63 (n)
                int r = li >> 6, f = li & 63;
                float v = Wo[(size_t)(k0 + r) * 512 + n0 + f];   // coalesced
                smem[f * 65 + r] = v;
            }
            __syncthreads();
            #pragma unroll
            for (int i2 = 0; i2 < 16; ++i2) {
                int li = t + i2 * 256;
                int f = li >> 6, r = li & 63;
                WoT[(size_t)(n0 + f) * KDIM + k0 + r] = f2bf(smem[f * 65 + r]);
            }
        }
    } else if (b < PREP_CAST0) {
        // ---- zero f1/f2/f1o/f2o/G: 136 blocks x 256 float4 = 544 KB ----
        int g = (b - PREP_Z0) * 256 + t;
        ((float4*)fzero)[g] = make_float4(0.f, 0.f, 0.f, 0.f);
    } else if (b < PREP_CSR0) {
        // ---- A_ext cast: 2 rows per block ----
        int half = t >> 7;            // 0..1
        int tt = t & 127;
        size_t i = (size_t)(b - PREP_CAST0) * 2 + half;
        float4 xv = ((const float4*)(x + i * FEAT))[tt];
        ushort4 o;
        o.x = f2bf(xv.x); o.y = f2bf(xv.y);
        o.z = f2bf(xv.z); o.w = f2bf(xv.w);
        *(ushort4*)(Abf + i * KDIM + 4 * tt) = o;
        if (tt < 16) {                // 64 adj_ad cols = 16 float4
            float4 av = ((const float4*)(adj_ad + i * 64))[tt];
            ushort4 o2;
            o2.x = f2bf(av.x); o2.y = f2bf(av.y);
            o2.z = f2bf(av.z); o2.w = f2bf(av.w);
            *(ushort4*)(Abf  + i * KDIM + 512 + 4 * tt) = o2;
            *(ushort4*)(Abf2 + i * KDIM + 512 + 4 * tt) = o2;
        }
    } else {
        // ---- CSR: one WAVE per row. 16 float4 loads in flight per lane,
        // 64-bit lane mask, wave prefix-sum, scatter. No barriers, no LDS.
        int l = t & 63;
        int i = (b - PREP_CSR0) * 4 + (t >> 6);
        const float4* row4 = (const float4*)(adj + (size_t)i * NN);
        float4 v[16];
        #pragma unroll
        for (int c2 = 0; c2 < 16; ++c2) v[c2] = row4[l + c2 * 64];
        unsigned long long mask = 0;
        #pragma unroll
        for (int c2 = 0; c2 < 16; ++c2) {
            unsigned m4 = (unsigned)(v[c2].x > 0.0f)
                        | ((unsigned)(v[c2].y > 0.0f) << 1)
                        | ((unsigned)(v[c2].z > 0.0f) << 2)
                        | ((unsigned)(v[c2].w > 0.0f) << 3);
            mask |= (unsigned long long)m4 << (4 * c2);
        }
        int c = __popcll(mask);
        int pre = c;
        #pragma unroll
        for (int off = 1; off < 64; off <<= 1) {
            int n = __shfl_up(pre, off);
            if (l >= off) pre += n;
        }
        int base = pre - c;           // exclusive prefix within wave
        if (l == 63) deg[i] = pre > MAXDEG ? MAXDEG : pre;
        int* colrow = cols + i * MAXDEG;
        int idx = base;
        while (mask) {
            int bit = (int)__ffsll(mask) - 1;
            mask &= mask - 1;
            int j = 4 * l + ((bit >> 2) << 8) + (bit & 3);
            if (idx < MAXDEG) colrow[idx] = j;
            ++idx;
        }
    }
}

// ---------------------------------------------------------------------------
// 64x64-tile GEMM, BK=64, 4 waves (2x2 quadrants of 32x32), TWO-PHASE
// double-buffered gload_lds pipeline: STAGE(next) issues BEFORE compute;
// ONE __syncthreads per K-step. XOR chunk swizzle (pre-swizzled global src,
// linear LDS dst, swizzled read).
// layer1: Cbf + f1/f2 dots.  layer2: f-dots + G = C@linW (Cbf write is dead).
__global__ __launch_bounds__(256) void gemm_bf16_dot_kernel(
    const bf16_t* __restrict__ A, const bf16_t* __restrict__ Bt,
    unsigned short* __restrict__ Cbf,
    const float* __restrict__ a1, const float* __restrict__ a2,
    float* __restrict__ f1, float* __restrict__ f2, int layer2,
    const float* __restrict__ linW, float* __restrict__ G) {
    __shared__ __align__(16) bf16_t Sb[2][2][64][64];   // [dbuf][A|B] 32 KB
    const int bm = blockIdx.x * 64;
    const int bn = blockIdx.y * 64;
    const int by = blockIdx.y;
    const int t  = threadIdx.x;
    const int l  = t & 63;
    const int w  = t >> 6;            // wave 0..3
    const int wr = w >> 1;            // wave row half (32 rows)
    const int wc = w & 1;             // wave col half (32 cols)
    const int c16 = l & 15;
    const int q8  = (l >> 4) * 8;     // k-elem offset of this lane's fragment
    const int r4  = (l >> 4) * 4;     // row offset of this lane's acc elems

    const bf16_t* Abase = A  + (size_t)bm * KDIM;
    const bf16_t* Bbase = Bt + (size_t)bn * KDIM;

    auto STAGE = [&](int d, int k0) {
        #pragma unroll
        for (int c = 0; c < 2; ++c) {
            int cb = c * 256 + w * 64;            // wave-uniform chunk base
            int li = cb + l;
            int r = li >> 3, pc = li & 7;
            int lc = pc ^ (r & 7);                // logical chunk to fetch
            gload16(Abase + (size_t)r * KDIM + k0 + lc * 8,
                    (char*)&Sb[d][0][0][0] + cb * 16);
        }
        #pragma unroll
        for (int c = 0; c < 2; ++c) {
            int cb = c * 256 + w * 64;
            int li = cb + l;
            int r = li >> 3, pc = li & 7;
            int lc = pc ^ (r & 7);
            gload16(Bbase + (size_t)r * KDIM + k0 + lc * 8,
                    (char*)&Sb[d][1][0][0] + cb * 16);
        }
    };

    f32x4_t acc[2][2] = {};
    int cur = 0;
    STAGE(0, 0);
    __syncthreads();                  // vmcnt(0)+barrier: buf0 ready
    for (int step = 0; step < KDIM / 64; ++step) {
        if (step + 1 < KDIM / 64) STAGE(cur ^ 1, (step + 1) * 64);
        #pragma unroll
        for (int kk = 0; kk < 64; kk += 32) {
            const int ck = (kk + q8) >> 3;        // logical chunk of fragment
            bf16x8_t af[2], bfr[2];
            #pragma unroll
            for (int mi = 0; mi < 2; ++mi) {
                int R = wr * 32 + mi * 16 + c16;
                af[mi] = *(const bf16x8_t*)&Sb[cur][0][R][(ck ^ (R & 7)) * 8];
            }
            #pragma unroll
            for (int ni = 0; ni < 2; ++ni) {
                int R = wc * 32 + ni * 16 + c16;
                bfr[ni] = *(const bf16x8_t*)&Sb[cur][1][R][(ck ^ (R & 7)) * 8];
            }
            #pragma unroll
            for (int mi = 0; mi < 2; ++mi)
                #pragma unroll
                for (int ni = 0; ni < 2; ++ni)
                    acc[mi][ni] = __builtin_amdgcn_mfma_f32_16x16x32_bf16(
                        af[mi], bfr[ni], acc[mi][ni], 0, 0, 0);
        }
        __syncthreads();              // drains next-tile loads AFTER compute
        cur ^= 1;
    }
    // C/D layout: col = lane&15, row = (lane>>4)*4 + reg
    float* Ct = (float*)&Sb[0][0][0][0];          // free after final barrier
    if (layer2) {
        // only the Ct LDS dump (for G) — bf16 C is dead in layer 2
        #pragma unroll
        for (int mi = 0; mi < 2; ++mi)
            #pragma unroll
            for (int ni = 0; ni < 2; ++ni)
                #pragma unroll
                for (int r = 0; r < 4; ++r)
                    Ct[(wr * 32 + mi * 16 + r4 + r) * 64
                       + wc * 32 + ni * 16 + c16] = acc[mi][ni][r];
    } else {
        #pragma unroll
        for (int mi = 0; mi < 2; ++mi)
            #pragma unroll
            for (int ni = 0; ni < 2; ++ni)
                #pragma unroll
                for (int r = 0; r < 4; ++r)
                    Cbf[(size_t)(bm + wr * 32 + mi * 16 + r4 + r) * FEAT
                        + bn + wc * 32 + ni * 16 + c16] = f2bf(acc[mi][ni][r]);
    }

    // fused f1/f2 dots (wave covers 32 of 64 cols; cross-wave via atomicAdd)
    float a1v[2], a2v[2];
    #pragma unroll
    for (int ni = 0; ni < 2; ++ni) {
        a1v[ni] = a1[bn + wc * 32 + ni * 16 + c16];
        a2v[ni] = a2[bn + wc * 32 + ni * 16 + c16];
    }
    float p1[2][4] = {}, p2[2][4] = {};
    #pragma unroll
    for (int mi = 0; mi < 2; ++mi)
        #pragma unroll
        for (int ni = 0; ni < 2; ++ni)
            #pragma unroll
            for (int r = 0; r < 4; ++r) {
                p1[mi][r] += acc[mi][ni][r] * a1v[ni];
                p2[mi][r] += acc[mi][ni][r] * a2v[ni];
            }
    #pragma unroll
    for (int off = 1; off <= 8; off <<= 1)
        #pragma unroll
        for (int mi = 0; mi < 2; ++mi)
            #pragma unroll
            for (int r = 0; r < 4; ++r) {
                p1[mi][r] += __shfl_xor(p1[mi][r], off);
                p2[mi][r] += __shfl_xor(p2[mi][r], off);
            }
    if (c16 == 0) {
        int fbase = layer2 ? 0 : by * NN;
        #pragma unroll
        for (int mi = 0; mi < 2; ++mi)
            #pragma unroll
            for (int r = 0; r < 4; ++r) {
                int row = bm + wr * 32 + mi * 16 + r4 + r;
                atomicAdd(&f1[fbase + row], p1[mi][r]);
                atomicAdd(&f2[fbase + row], p2[mi][r]);
            }
    }
    // ---- G partial: G[bm+row][cls] += sum_c Ct[row][c]*linW[bn+c][cls] ----
    if (layer2) {
        __syncthreads();              // Ct fully written
        int row = t >> 2;             // 0..63
        int cls0 = (t & 3) * 4;       // 4 consecutive classes
        float pg[4] = {};
        #pragma unroll 8
        for (int c = 0; c < 64; ++c) {
            float cv = Ct[row * 64 + c];
            float4 wv = *(const float4*)&linW[(size_t)(bn + c) * NCLS + cls0];
            pg[0] += cv * wv.x; pg[1] += cv * wv.y;
            pg[2] += cv * wv.z; pg[3] += cv * wv.w;
        }
        #pragma unroll
        for (int j = 0; j < 4; ++j)
            atomicAdd(&G[(size_t)(bm + row) * NCLS + cls0 + j], pg[j]);
    }
}

// ---------------------------------------------------------------------------
// Layer-1 sparse attention + ELU epilogue -> cols 0..511 of A_ext layer 2.
// Phase B is now 16-granular (unroll 2, wave h takes k ≡ h mod 8): mean
// degree ~42 means dpad drops 64 -> 48 for most rows (−25% gather work vs
// the 32-granular unroll-4 version).
__global__ __launch_bounds__(512) void att1_kernel(
    const bf16_t* __restrict__ Hbf, const float* __restrict__ f1,
    const float* __restrict__ f2, const int* __restrict__ deg,
    const int* __restrict__ cols, bf16_t* __restrict__ outbf) {
    int i = blockIdx.x;
    int tid = threadIdx.x;
    int h = tid >> 6;                 // wave id (phase A: head; phase B: slot)
    int l = tid & 63;
    __shared__ int jl[MAXDEG];
    __shared__ float se[NHEADS][MAXDEG];
    __shared__ float part[NHEADS][FEAT];   // 16 KB
    __shared__ float sinv[NHEADS];
    __shared__ int sdeg;
    if (tid == 0) sdeg = deg[i];
    __syncthreads();
    int d = sdeg;
    int dpad = (d + 15) & ~15;        // multiple of 16 (8 waves x 2 unroll)
    for (int k = tid; k < dpad; k += 512)
        jl[k] = (k < d) ? cols[i * MAXDEG + k] : i;   // pad: self, weight 0
    __syncthreads();
    // ---- phase A: scores for head h ----
    float fi = f1[h * NN + i];
    float lmax = -1e30f;
    for (int k = l; k < d; k += 64) {
        float e = fi + f2[h * NN + jl[k]];
        e = e > 0.0f ? e : ALPHA * e;
        se[h][k] = e;
        lmax = fmaxf(lmax, e);
    }
    for (int off = 32; off; off >>= 1) lmax = fmaxf(lmax, __shfl_down(lmax, off));
    float m = __shfl(lmax, 0);
    float ls = 0.0f;
    for (int k = l; k < d; k += 64) {
        float p = __expf(se[h][k] - m);
        se[h][k] = p;
        ls += p;
    }
    for (int k = d + l; k < dpad; k += 64) se[h][k] = 0.0f;
    for (int off = 32; off; off >>= 1) ls += __shfl_down(ls, off);
    if (l == 0) sinv[h] = 1.0f / ls;
    __syncthreads();                  // se/sinv now read cross-wave
    // ---- phase B: whole-row gather (wave h takes k ≡ h mod 8, unroll 2) ----
    const int myhead = l >> 3;        // head of this lane's output columns
    float acc[8] = {};
    for (int k0 = 0; k0 < dpad; k0 += 16) {
        float pw[2];
        const bf16_t* rp[2];
        #pragma unroll
        for (int j = 0; j < 2; ++j) {
            int k = k0 + j * 8 + h;                  // k < dpad guaranteed
            pw[j] = se[myhead][k];
            rp[j] = Hbf + (size_t)jl[k] * FEAT + l * 8;
        }
        #pragma unroll
        for (int j = 0; j < 2; ++j) {
            us8_t v = *(const us8_t*)rp[j];
            float p = pw[j];
            #pragma unroll
            for (int q = 0; q < 8; ++q) acc[q] += p * bfu2f(v[q]);
        }
    }
    *(float4*)&part[h][l * 8]     = make_float4(acc[0], acc[1], acc[2], acc[3]);
    *(float4*)&part[h][l * 8 + 4] = make_float4(acc[4], acc[5], acc[6], acc[7]);
    __syncthreads();
    // ---- epilogue: thread tid handles output column tid ----
    {
        float sum = 0.0f;
        #pragma unroll
        for (int w2 = 0; w2 < NHEADS; ++w2) sum += part[w2][tid];
        float o = sum * sinv[tid >> 6];
        o = o > 0.0f ? o : __expf(o) - 1.0f;         // ELU
        ((unsigned short*)outbf)[(size_t)i * KDIM + tid] = f2bf(o);
    }
}

// ---------------------------------------------------------------------------
// Layer-2 attention via G = H2@linW (4096x16): per row gather only d x 16
// floats, then bias+ELU+log_softmax. Block = 256 (tiny LDS, deep occupancy).
__global__ __launch_bounds__(256) void att2_final_kernel(
    const float* __restrict__ G, const float* __restrict__ f1,
    const float* __restrict__ f2, const int* __restrict__ deg,
    const int* __restrict__ cols, const float* __restrict__ linb,
    float* __restrict__ out) {
    int i = blockIdx.x;
    int t = threadIdx.x;
    __shared__ int jl[MAXDEG];
    __shared__ float sp[MAXDEG];
    __shared__ float red[4];
    __shared__ float clsred[16][NCLS];
    __shared__ float sl[NCLS];
    __shared__ int sdeg;
    if (t == 0) sdeg = deg[i];
    __syncthreads();
    int d = sdeg;
    int dpad = (d + 15) & ~15;        // multiple of 16 (16 gather slots)
    if (t < dpad) jl[t] = (t < d) ? cols[i * MAXDEG + t] : i;
    __syncthreads();
    float e = 0.0f, lmax = -1e30f;
    if (t < d) {
        e = f1[i] + f2[jl[t]];
        e = e > 0.0f ? e : ALPHA * e;
        lmax = e;
    }
    for (int off = 32; off; off >>= 1) lmax = fmaxf(lmax, __shfl_down(lmax, off));
    if ((t & 63) == 0) red[t >> 6] = lmax;
    __syncthreads();
    float m = fmaxf(fmaxf(red[0], red[1]), fmaxf(red[2], red[3]));
    float p = 0.0f;
    if (t < d) p = __expf(e - m);
    if (t < dpad) sp[t] = p;          // pads write 0
    float ls = p;
    for (int off = 32; off; off >>= 1) ls += __shfl_down(ls, off);
    __syncthreads();                  // red[] reads done before overwrite
    if ((t & 63) == 0) red[t >> 6] = ls;
    __syncthreads();                  // publishes sp[] + red[]
    float s = red[0] + red[1] + red[2] + red[3];
    float inv = 1.0f / s;
    // ---- 16-wide gather: slot = t>>4 takes k ≡ slot (mod 16), cls = t&15 --
    {
        int slot = t >> 4;
        int cls  = t & 15;
        float fa[4] = {};             // 4 independent chains
        for (int k = slot; k < dpad; k += 16)
            fa[(k >> 4) & 3] += sp[k] * G[(size_t)jl[k] * NCLS + cls];
        clsred[slot][cls] = (fa[0] + fa[1]) + (fa[2] + fa[3]);
    }
    __syncthreads();
    if (t < NCLS) {
        float dot = 0.0f;
        #pragma unroll
        for (int seg = 0; seg < 16; ++seg) dot += clsred[seg][t];
        float logit = linb[t] + dot * inv;
        logit = logit > 0.0f ? logit : __expf(logit) - 1.0f;   // ELU
        sl[t] = logit;
    }
    __syncthreads();
    if (t < NCLS) {
        float mm = sl[0];
        #pragma unroll
        for (int c = 1; c < NCLS; ++c) mm = fmaxf(mm, sl[c]);
        float ssum = 0.0f;
        #pragma unroll
        for (int c = 0; c < NCLS; ++c) ssum += __expf(sl[c] - mm);
        out[i * NCLS + t] = sl[t] - mm - logf(ssum);
    }
}

// ---------------------------------------------------------------------------
extern "C" void kernel_launch(void* const* d_in, const int* in_sizes, int n_in,
                              void* d_out, int out_size, void* d_ws, size_t ws_size,
                              hipStream_t stream) {
    const float* x        = (const float*)d_in[0];
    const float* rel      = (const float*)d_in[1];
    // d_in[2] rel_dict: unused (non-math constant per reference)
    const float* adj      = (const float*)d_in[3];
    const float* adj_ad   = (const float*)d_in[4];
    const float* W_heads  = (const float*)d_in[5];
    const float* a1_heads = (const float*)d_in[6];
    const float* a2_heads = (const float*)d_in[7];
    const float* W_out    = (const float*)d_in[8];
    const float* a1_out   = (const float*)d_in[9];
    const float* a2_out   = (const float*)d_in[10];
    const float* lin_W    = (const float*)d_in[11];
    const float* lin_b    = (const float*)d_in[12];
    float* out = (float*)d_out;

    char* ws = (char*)d_ws;
    bf16_t* Abf  = (bf16_t*)(ws);                                 // 4.5 MB [4096][576] layer-1 A_ext
    bf16_t* Abf2 = (bf16_t*)(ws + (5u  << 20));                   // 4.5 MB [4096][576] layer-2 A_ext
    bf16_t* Hbf1 = (bf16_t*)(ws + (10u << 20));                   // 4 MB  [4096][512] layer-1 H (gather)
    bf16_t* Hbf2 = (bf16_t*)(ws + (14u << 20));                   // 4 MB  (unused in layer2 now)
    bf16_t* WcT  = (bf16_t*)(ws + (18u << 20));                   // 576 KB [512][576] B_ext layer 1
    bf16_t* WoT  = (bf16_t*)(ws + (19u << 20));                   // 576 KB [512][576] B_ext layer 2
    float*  f1   = (float*) (ws + (20u << 20));                   // 128 KB [8,4096]
    float*  f2   = (float*) (ws + (20u << 20) + (128u << 10));    // 128 KB
    float*  f1o  = (float*) (ws + (20u << 20) + (256u << 10));    // 16 KB
    float*  f2o  = (float*) (ws + (20u << 20) + (272u << 10));    // 16 KB
    float*  G    = (float*) (ws + (20u << 20) + (288u << 10));    // 256 KB [4096][16]
    int*    deg  = (int*)   (ws + (20u << 20) + (544u << 10));    // 16 KB
    int*    cols = (int*)   (ws + (21u << 20));                   // 2 MB  [4096,128]

    // fused front-end: relW + transposes + zero(f,G) + A_ext casts + CSR
    prep_kernel<<<PREP_NBLK, 256, 0, stream>>>(
        adj, deg, cols, adj_ad, rel, x, Abf, Abf2, W_heads, W_out,
        (unsigned short*)WcT, (unsigned short*)WoT, f1);
    // layer-1 GEMM (2-phase dbuf pipeline) + f1/f2 dots
    gemm_bf16_dot_kernel<<<dim3(64, 8), 256, 0, stream>>>(
        Abf, WcT, (unsigned short*)Hbf1, a1_heads, a2_heads, f1, f2, 0,
        nullptr, nullptr);
    // layer-1 attention + ELU epilogue -> Abf2 cols 0..511
    att1_kernel<<<NN, 512, 0, stream>>>(Hbf1, f1, f2, deg, cols, Abf2);
    // layer-2 GEMM (2-phase dbuf) + f1o/f2o dots + G = H2@linW (no dead C)
    gemm_bf16_dot_kernel<<<dim3(64, 8), 256, 0, stream>>>(
        Abf2, WoT, (unsigned short*)Hbf2, a1_out, a2_out, f1o, f2o, 1,
        lin_W, G);
    // layer-2 attention on G (16-wide gather) + classifier + log_softmax
    att2_final_kernel<<<NN, 256, 0, stream>>>(G, f1o, f2o, deg, cols, lin_b, out);
}